// Round 5
// baseline (520.933 us; speedup 1.0000x reference)
//
#include <hip/hip_runtime.h>
#include <hip/hip_bf16.h>

#define NTOT 8192
#define DDIM 256
#define RTILE 16                // rows per attn block
#define JSPL 2                  // j-split across blocks (partials + combine)
#define JBLK (NTOT / JSPL)      // 4096 j per block
#define JWAVE (JBLK / 2)        // 2048 j per wave (jc = 0/1)
#define NITER (JWAVE / 32)      // 64 j-tiles per wave
#define NTSTR 131584            // hTf nt-stride in elems: 257*64*8
#define HTF_ELEMS (16 * NTSTR)

typedef __attribute__((ext_vector_type(8))) short short8;
typedef __attribute__((ext_vector_type(4))) float floatx4;
typedef __attribute__((ext_vector_type(4))) int intx4;

static __device__ __forceinline__ short bfp(float f) {
  __hip_bfloat16 b = __float2bfloat16(f);
  return *(short*)&b;
}

// ------- per-row scores: s1[i] = h[i,:]@a[:256], s2[j] = h[j,:]@a[256:]
__global__ __launch_bounds__(256) void gat_scores(const float* __restrict__ h,
                                                  const float* __restrict__ a,
                                                  float* __restrict__ s1,
                                                  float* __restrict__ s2) {
  int row  = blockIdx.x * 4 + (threadIdx.x >> 6);
  int lane = threadIdx.x & 63;
  const float* hr = h + (size_t)row * DDIM;
  float p1 = 0.f, p2 = 0.f;
#pragma unroll
  for (int k = 0; k < DDIM / 64; ++k) {
    int idx  = lane + 64 * k;
    float hv = hr[idx];
    p1 += hv * a[idx];
    p2 += hv * a[DDIM + idx];
  }
#pragma unroll
  for (int off = 32; off > 0; off >>= 1) {
    p1 += __shfl_down(p1, off, 64);
    p2 += __shfl_down(p2, off, 64);
  }
  if (lane == 0) { s1[row] = p1; s2[row] = p2; }
}

// ---------------- pack h -> fragment-major bf16 hTf (padded nt-stride) ------
// hTf[((n*257 + jblk)*64 + lane)*8 + i] = H[jblk*32 + (lane>>4)*8 + i][n*16 + (lane&15)]
__global__ __launch_bounds__(256) void gat_hpack(const float* __restrict__ h,
                                                 ushort* __restrict__ hTf) {
  __shared__ float tile[64][257];
  const int t    = threadIdx.x;
  const int lane = t & 63;
  const int w    = t >> 6;
  const int quad = lane >> 4;
  const int c    = lane & 15;
  const int i0   = blockIdx.x * 64;

#pragma unroll
  for (int it = 0; it < 16; ++it) {
    int r = it * 4 + w;
    float4 v = *(const float4*)(h + (size_t)(i0 + r) * DDIM + lane * 4);
    tile[r][lane * 4 + 0] = v.x; tile[r][lane * 4 + 1] = v.y;
    tile[r][lane * 4 + 2] = v.z; tile[r][lane * 4 + 3] = v.w;
  }
  __syncthreads();

#pragma unroll
  for (int k = 0; k < 4; ++k) {
    const int n = 4 * k + w;
#pragma unroll
    for (int jbl = 0; jbl < 2; ++jbl) {
      short8 vv;
#pragma unroll
      for (int i = 0; i < 8; ++i) {
        float f = tile[jbl * 32 + quad * 8 + i][n * 16 + c];
        vv[i] = bfp(f);
      }
      *(short8*)(hTf + ((size_t)(n * 257 + i0 / 32 + jbl) * 64 + lane) * 8) = vv;
    }
  }
}

// ---------------- barrier-free fused softmax-num + P@h partials via MFMA ----
// grid (512, 2) x 256 thr (4 waves). Block (bx, jb): rows [16bx,+16),
// j in [4096jb,+4096). Wave (ch = w&1, jc = w>>1): cols [128ch,+128),
// j-half [2048jc,+2048). ~110 VGPR -> 4 waves/SIMD, 4 blocks/CU, NO barrier
// in the loop. P-build: p = (adj>0) ? exp(max(e, .01e)) : 0, e = s1[i]+s2[j]
// (leaky(x) = max(x, .01x); one __expf on the idle trans pipe).
__global__ __launch_bounds__(256, 4) void gat_attn(const ushort* __restrict__ hTf,
                                                   const int* __restrict__ adj,
                                                   const float* __restrict__ s1,
                                                   const float* __restrict__ s2,
                                                   float* __restrict__ pout,
                                                   float* __restrict__ plp) {
  __shared__ float slab[2][32][64];   // jc=1 acc dump: [ch][q*4+r][lane] = 16 KB
  __shared__ float lpred[2][16];      // jc=1 denom partials per ch

  const int t    = threadIdx.x;
  const int lane = t & 63;
  const int w    = t >> 6;
  const int quad = lane >> 4;
  const int c    = lane & 15;
  const int ch   = w & 1;
  const int jc   = w >> 1;
  const int r0   = blockIdx.x * RTILE;
  const int jb   = blockIdx.y;
  const int j0   = jb * JBLK + jc * JWAVE;

  const float a1 = s1[r0 + c];        // this lane's attention-row constant

  const int*    ap = adj + (size_t)(r0 + c) * NTOT + j0 + quad * 8;
  const float*  sp = s2 + j0 + quad * 8;
  const ushort* hb = hTf + (size_t)(ch * 8) * NTSTR + ((size_t)(j0 / 32) * 64 + lane) * 8;

  floatx4 acc[8];
#pragma unroll
  for (int q = 0; q < 8; ++q) acc[q] = (floatx4){0.f, 0.f, 0.f, 0.f};

  float lp = 0.f;
  short8 bA[4], bB[4];
  intx4  aj0, aj1;
  float4 sv0, sv1;

  #define LDA(jt)                                                              \
    {                                                                          \
      const int* p_ = ap + (size_t)(jt) * 32;                                  \
      aj0 = __builtin_nontemporal_load((const intx4*)p_);                      \
      aj1 = __builtin_nontemporal_load((const intx4*)(p_ + 4));                \
      sv0 = *(const float4*)(sp + (jt) * 32);                                  \
      sv1 = *(const float4*)(sp + (jt) * 32 + 4);                              \
    }
  #define LDBA(jt)                                                             \
    _Pragma("unroll")                                                          \
    for (int q = 0; q < 4; ++q)                                                \
      bA[q] = *(const short8*)(hb + (size_t)(jt) * 512 + (size_t)q * NTSTR);
  #define LDBB(jt)                                                             \
    _Pragma("unroll")                                                          \
    for (int q = 0; q < 4; ++q)                                                \
      bB[q] = *(const short8*)(hb + (size_t)(jt) * 512 + (size_t)(4 + q) * NTSTR);

  // prologue
  LDBA(0)
  LDBB(0)
  LDA(0)

  for (int jt = 0; jt < NITER; ++jt) {
    const int jn = (jt + 1) & (NITER - 1);   // wrapped (branch-free)

    // ---- P-build for this tile ----
    const float sarr[8] = {sv0.x, sv0.y, sv0.z, sv0.w, sv1.x, sv1.y, sv1.z, sv1.w};
    const int   aarr[8] = {aj0[0], aj0[1], aj0[2], aj0[3], aj1[0], aj1[1], aj1[2], aj1[3]};
    short8 pa;
#pragma unroll
    for (int i = 0; i < 8; ++i) {
      const float e  = a1 + sarr[i];
      const float l  = fmaxf(e, 0.01f * e);
      const float pe = __expf(l);
      const float p  = (aarr[i] > 0) ? pe : 0.f;
      lp += p;
      pa[i] = bfp(p);
    }

    // ---- prefetch next adj + s2 (full-iteration distance) ----
    LDA(jn)

    // ---- MFMA col-frags 0-3, refill bA ----
#pragma unroll
    for (int q = 0; q < 4; ++q)
      acc[q] = __builtin_amdgcn_mfma_f32_16x16x32_bf16(pa, bA[q], acc[q], 0, 0, 0);
    LDBA(jn)

    // ---- MFMA col-frags 4-7, refill bB ----
#pragma unroll
    for (int q = 0; q < 4; ++q)
      acc[4 + q] = __builtin_amdgcn_mfma_f32_16x16x32_bf16(pa, bB[q], acc[4 + q], 0, 0, 0);
    LDBB(jn)
  }
  #undef LDA
  #undef LDBA
  #undef LDBB

  // ---- denom partial: sum quads -> every lane has row-c sum over wave's j ----
  lp += __shfl_xor(lp, 16, 64);
  lp += __shfl_xor(lp, 32, 64);

  // ---- jc-pair merge (single barrier) ----
  if (jc == 1) {
#pragma unroll
    for (int q = 0; q < 8; ++q)
#pragma unroll
      for (int r = 0; r < 4; ++r) slab[ch][q * 4 + r][lane] = acc[q][r];
    if (lane < 16) lpred[ch][lane] = lp;
  }
  __syncthreads();
  if (jc == 0) {
#pragma unroll
    for (int q = 0; q < 8; ++q)
#pragma unroll
      for (int r = 0; r < 4; ++r) acc[q][r] += slab[ch][q * 4 + r][lane];
    lp += lpred[ch][c];

    float* pob = pout + (size_t)jb * NTOT * DDIM;
#pragma unroll
    for (int q = 0; q < 8; ++q)
#pragma unroll
      for (int r = 0; r < 4; ++r)
        pob[(size_t)(r0 + quad * 4 + r) * DDIM + ch * 128 + q * 16 + c] = acc[q][r];
    if (ch == 0 && quad == 0) plp[(size_t)jb * NTOT + r0 + c] = lp;
  }
}

// ---------------- combine the 2 j-half partials, divide by denom ------------
__global__ __launch_bounds__(256) void gat_combine(const float* __restrict__ pout,
                                                   const float* __restrict__ plp,
                                                   float* __restrict__ out) {
  const int idx = blockIdx.x * 256 + threadIdx.x;   // float4-group index
  const int row = idx >> 6;                          // 64 float4 per row
  float4 a = ((const float4*)pout)[idx];
  float4 b = ((const float4*)(pout + (size_t)NTOT * DDIM))[idx];
  float inv = 1.f / (plp[row] + plp[NTOT + row]);
  float4 r;
  r.x = (a.x + b.x) * inv;
  r.y = (a.y + b.y) * inv;
  r.z = (a.z + b.z) * inv;
  r.w = (a.w + b.w) * inv;
  __builtin_nontemporal_store(r.x, &((float*)out)[idx * 4 + 0]);
  __builtin_nontemporal_store(r.y, &((float*)out)[idx * 4 + 1]);
  __builtin_nontemporal_store(r.z, &((float*)out)[idx * 4 + 2]);
  __builtin_nontemporal_store(r.w, &((float*)out)[idx * 4 + 3]);
}

extern "C" void kernel_launch(void* const* d_in, const int* in_sizes, int n_in,
                              void* d_out, int out_size, void* d_ws, size_t ws_size,
                              hipStream_t stream) {
  const float* h   = (const float*)d_in[0];
  const int*   adj = (const int*)d_in[1];
  const float* a   = (const float*)d_in[2];
  float* out = (float*)d_out;

  float*    s1    = (float*)d_ws;                        // 8192 f32
  float*    s2    = s1 + NTOT;                           // 8192 f32
  ushort*   hTf   = (ushort*)(s2 + NTOT);                // 4.21 MB bf16 (16B-aligned at 64KB)
  float*    pout  = (float*)(hTf + HTF_ELEMS);           // 2 x 8192 x 256 f32 = 16 MB
  float*    plp   = pout + (size_t)JSPL * NTOT * DDIM;   // 2 x 8192 f32

  gat_scores<<<NTOT / 4, 256, 0, stream>>>(h, a, s1, s2);
  gat_hpack<<<NTOT / 64, 256, 0, stream>>>(h, hTf);
  gat_attn<<<dim3(NTOT / RTILE, JSPL), 256, 0, stream>>>(hTf, adj, s1, s2, pout, plp);
  gat_combine<<<(NTOT * DDIM / 4) / 256, 256, 0, stream>>>(pout, plp, out);
}

// Round 6
// 519.690 us; speedup vs baseline: 1.0024x; 1.0024x over previous
//
#include <hip/hip_runtime.h>
#include <hip/hip_bf16.h>

#define NTOT 8192
#define DDIM 256
#define ROWS 32                 // rows per attn block
#define JWAVE 2048              // j per wave (jg = 0..3)
#define NITER (JWAVE / 32)      // 64 j-tiles per wave
#define NTSTR 131584            // hTf nt-stride in elems: 257*64*8
#define HTF_ELEMS (16 * NTSTR)

typedef __attribute__((ext_vector_type(8))) short short8;
typedef __attribute__((ext_vector_type(4))) float floatx4;
typedef __attribute__((ext_vector_type(4))) int intx4;

static __device__ __forceinline__ short bfp(float f) {
  __hip_bfloat16 b = __float2bfloat16(f);
  return *(short*)&b;
}

// ------- per-row exp tables: rc=(e^s1, e^.01s1), etab=(e^s2, e^.01s2)
// exp(leaky(s1+s2)) = max(e^s1*e^s2, e^.01s1*e^.01s2)  (exact: monotone cases)
__global__ __launch_bounds__(256) void gat_scores(const float* __restrict__ h,
                                                  const float* __restrict__ a,
                                                  float2* __restrict__ rc,
                                                  float2* __restrict__ etab) {
  int row  = blockIdx.x * 4 + (threadIdx.x >> 6);
  int lane = threadIdx.x & 63;
  const float* hr = h + (size_t)row * DDIM;
  float p1 = 0.f, p2 = 0.f;
#pragma unroll
  for (int k = 0; k < DDIM / 64; ++k) {
    int idx  = lane + 64 * k;
    float hv = hr[idx];
    p1 += hv * a[idx];
    p2 += hv * a[DDIM + idx];
  }
#pragma unroll
  for (int off = 32; off > 0; off >>= 1) {
    p1 += __shfl_down(p1, off, 64);
    p2 += __shfl_down(p2, off, 64);
  }
  if (lane == 0) {
    rc[row]   = make_float2(__expf(p1), __expf(0.01f * p1));
    etab[row] = make_float2(__expf(p2), __expf(0.01f * p2));
  }
}

// ---------------- pack h -> fragment-major bf16 hTf (padded nt-stride) ------
// hTf[((n*257 + jblk)*64 + lane)*8 + i] = H[jblk*32 + (lane>>4)*8 + i][n*16 + (lane&15)]
__global__ __launch_bounds__(256) void gat_hpack(const float* __restrict__ h,
                                                 ushort* __restrict__ hTf) {
  __shared__ float tile[64][257];
  const int t    = threadIdx.x;
  const int lane = t & 63;
  const int w    = t >> 6;
  const int quad = lane >> 4;
  const int c    = lane & 15;
  const int i0   = blockIdx.x * 64;

#pragma unroll
  for (int it = 0; it < 16; ++it) {
    int r = it * 4 + w;
    float4 v = *(const float4*)(h + (size_t)(i0 + r) * DDIM + lane * 4);
    tile[r][lane * 4 + 0] = v.x; tile[r][lane * 4 + 1] = v.y;
    tile[r][lane * 4 + 2] = v.z; tile[r][lane * 4 + 3] = v.w;
  }
  __syncthreads();

#pragma unroll
  for (int k = 0; k < 4; ++k) {
    const int n = 4 * k + w;
#pragma unroll
    for (int jbl = 0; jbl < 2; ++jbl) {
      short8 vv;
#pragma unroll
      for (int i = 0; i < 8; ++i) {
        float f = tile[jbl * 32 + quad * 8 + i][n * 16 + c];
        vv[i] = bfp(f);
      }
      *(short8*)(hTf + ((size_t)(n * 257 + i0 / 32 + jbl) * 64 + lane) * 8) = vv;
    }
  }
}

// ---------------- barrier-free fused softmax + P@h via MFMA -----------------
// grid 256 x 1024 thr (16 waves) = exactly 1 block/CU, 4 waves/SIMD.
// Block: rows [32bx,+32) x all 8192 j. Wave (rg=w&1, cg=(w>>1)&1, jg=w>>2):
// rows [16rg,+16), cols [128cg,+128), j [2048jg,+2048). ~110 VGPR.
// NO barrier in the K-loop; sched_barrier(0) pins each prefetch group so the
// compiler cannot sink loads to their uses (R5 failure: VGPR 44 = un-pipelined).
__global__ __launch_bounds__(1024, 4) void gat_attn(const ushort* __restrict__ hTf,
                                                    const int* __restrict__ adj,
                                                    const float2* __restrict__ rc,
                                                    const float2* __restrict__ etab,
                                                    float* __restrict__ out) {
  __shared__ float slab[8][32][64];   // jg merge buffers: 64 KB
  __shared__ float lsum[4][32];       // per-jg denom partials

  const int t    = threadIdx.x;
  const int lane = t & 63;
  const int w    = t >> 6;
  const int quad = lane >> 4;
  const int c    = lane & 15;
  const int rg   = w & 1;
  const int cg   = (w >> 1) & 1;
  const int jg   = w >> 2;
  const int r0   = blockIdx.x * ROWS;
  const int rb   = r0 + rg * 16;      // this wave's 16-row base
  const int j0   = jg * JWAVE;

  const float2 rcv = rc[rb + c];
  const float E1 = rcv.x, E2 = rcv.y;

  const int*    ap  = adj + (size_t)(rb + c) * NTOT + j0 + quad * 8;
  const float*  etb = (const float*)(etab + j0 + quad * 8);
  const ushort* hb  = hTf + (size_t)(8 * cg) * NTSTR + (size_t)(j0 / 32) * 512 + lane * 8;

  floatx4 acc[8];
#pragma unroll
  for (int q = 0; q < 8; ++q) acc[q] = (floatx4){0.f, 0.f, 0.f, 0.f};

  float lp = 0.f;
  short8 bA[4], bB[4];
  intx4  aj0, aj1;
  float4 ea, eb, ec, ed;

  #define LDA(jt)                                                              \
    {                                                                          \
      const int* p_ = ap + (size_t)(jt) * 32;                                  \
      aj0 = __builtin_nontemporal_load((const intx4*)p_);                      \
      aj1 = __builtin_nontemporal_load((const intx4*)(p_ + 4));                \
    }
  #define LDE(jt)                                                              \
    {                                                                          \
      const float* e_ = etb + (size_t)(jt) * 64;                               \
      ea = ((const float4*)e_)[0];                                             \
      eb = ((const float4*)e_)[1];                                             \
      ec = ((const float4*)e_)[2];                                             \
      ed = ((const float4*)e_)[3];                                             \
    }
  #define LDBA(jt)                                                             \
    _Pragma("unroll")                                                          \
    for (int q = 0; q < 4; ++q)                                                \
      bA[q] = *(const short8*)(hb + (size_t)(jt) * 512 + (size_t)q * NTSTR);
  #define LDBB(jt)                                                             \
    _Pragma("unroll")                                                          \
    for (int q = 0; q < 4; ++q)                                                \
      bB[q] = *(const short8*)(hb + (size_t)(jt) * 512 + (size_t)(4 + q) * NTSTR);

  // prologue
  LDBA(0)
  LDBB(0)
  LDA(0)
  LDE(0)

  for (int jt = 0; jt < NITER; ++jt) {
    const int jn = (jt + 1) & (NITER - 1);   // wrapped (branch-free)

    // ---- P-build: p = (adj>0) ? max(E1*t1, E2*t2) : 0 ----
    const int   am[8] = {aj0[0], aj0[1], aj0[2], aj0[3], aj1[0], aj1[1], aj1[2], aj1[3]};
    const float tp[16] = {ea.x, ea.y, ea.z, ea.w, eb.x, eb.y, eb.z, eb.w,
                          ec.x, ec.y, ec.z, ec.w, ed.x, ed.y, ed.z, ed.w};
    short8 pa;
#pragma unroll
    for (int i = 0; i < 8; ++i) {
      const float p = (am[i] > 0) ? fmaxf(E1 * tp[2 * i], E2 * tp[2 * i + 1]) : 0.f;
      lp += p;
      pa[i] = bfp(p);
    }

    // ---- prefetch next adj + etab; pin (no sinking past this point) ----
    LDA(jn)
    LDE(jn)
    __builtin_amdgcn_sched_barrier(0);

    // ---- MFMA col-frags 0-3, refill bA, pin ----
#pragma unroll
    for (int q = 0; q < 4; ++q)
      acc[q] = __builtin_amdgcn_mfma_f32_16x16x32_bf16(pa, bA[q], acc[q], 0, 0, 0);
    LDBA(jn)
    __builtin_amdgcn_sched_barrier(0);

    // ---- MFMA col-frags 4-7, refill bB, pin ----
#pragma unroll
    for (int q = 0; q < 4; ++q)
      acc[4 + q] = __builtin_amdgcn_mfma_f32_16x16x32_bf16(pa, bB[q], acc[4 + q], 0, 0, 0);
    LDBB(jn)
    __builtin_amdgcn_sched_barrier(0);
  }
  #undef LDA
  #undef LDE
  #undef LDBA
  #undef LDBB

  // ---- denom: fold quads -> every lane holds row-(rb+c) sum over wave's j ----
  lp += __shfl_xor(lp, 16, 64);
  lp += __shfl_xor(lp, 32, 64);
  if (cg == 0 && lane < 16) lsum[jg][rg * 16 + lane] = lp;

  // ---- jg-tree merge: 4 -> 2 -> 1 ----
  const int sidx = rg * 2 + cg;
  if (jg >= 2) {
#pragma unroll
    for (int q = 0; q < 8; ++q)
#pragma unroll
      for (int r = 0; r < 4; ++r)
        slab[(jg - 2) * 4 + sidx][q * 4 + r][lane] = acc[q][r];
  }
  __syncthreads();
  if (jg < 2) {
#pragma unroll
    for (int q = 0; q < 8; ++q)
#pragma unroll
      for (int r = 0; r < 4; ++r)
        acc[q][r] += slab[jg * 4 + sidx][q * 4 + r][lane];
  }
  __syncthreads();
  if (jg == 1) {
#pragma unroll
    for (int q = 0; q < 8; ++q)
#pragma unroll
      for (int r = 0; r < 4; ++r)
        slab[sidx][q * 4 + r][lane] = acc[q][r];
  }
  __syncthreads();
  if (jg == 0) {
    float linv[4];
#pragma unroll
    for (int r = 0; r < 4; ++r) {
      const int lr = rg * 16 + quad * 4 + r;
      linv[r] = 1.f / (lsum[0][lr] + lsum[1][lr] + lsum[2][lr] + lsum[3][lr]);
    }
#pragma unroll
    for (int q = 0; q < 8; ++q)
#pragma unroll
      for (int r = 0; r < 4; ++r) {
        float v = acc[q][r] + slab[sidx][q * 4 + r][lane];
        __builtin_nontemporal_store(
            v * linv[r],
            &out[(size_t)(rb + quad * 4 + r) * DDIM + cg * 128 + q * 16 + c]);
      }
  }
}

extern "C" void kernel_launch(void* const* d_in, const int* in_sizes, int n_in,
                              void* d_out, int out_size, void* d_ws, size_t ws_size,
                              hipStream_t stream) {
  const float* h   = (const float*)d_in[0];
  const int*   adj = (const int*)d_in[1];
  const float* a   = (const float*)d_in[2];
  float* out = (float*)d_out;

  float2*   rc    = (float2*)d_ws;                       // 8192 float2 = 64 KB
  float2*   etab  = rc + NTOT;                           // 8192 float2 = 64 KB
  ushort*   hTf   = (ushort*)(etab + NTOT);              // 4.21 MB bf16 (16B-aligned at 128KB)

  gat_scores<<<NTOT / 4, 256, 0, stream>>>(h, a, rc, etab);
  gat_hpack<<<NTOT / 64, 256, 0, stream>>>(h, hTf);
  gat_attn<<<NTOT / ROWS, 1024, 0, stream>>>(hTf, adj, rc, etab, out);
}